// Round 15
// baseline (230.586 us; speedup 1.0000x reference)
//
#include <hip/hip_runtime.h>

#define NNODES 40000
#define NEDGES 640000
#define DIN 128
#define DHID 256
#define DOUT 47
#define NCNT 40960
#define NPART (NCNT / 256)

typedef __attribute__((ext_vector_type(8))) short short8;
typedef __attribute__((ext_vector_type(4))) float f32x4;

#define GLD16(gp, lp)                                                        \
    __builtin_amdgcn_global_load_lds(                                        \
        (const __attribute__((address_space(1))) void*)(gp),                 \
        (__attribute__((address_space(3))) void*)(lp), 16, 0, 0)

__device__ inline float bf2f(unsigned short u) {
    union { unsigned int i; float f; } c; c.i = ((unsigned int)u) << 16; return c.f;
}
__device__ inline unsigned short f2bf(float f) {
    union { float f; unsigned int i; } c; c.f = f;
    unsigned int x = c.i;
    x += 0x7fff + ((x >> 16) & 1);  // RNE
    return (unsigned short)(x >> 16);
}

// ---------------- CSR build (R12 proved coop grid.sync is ~20x worse than boundaries) ----------------
__global__ void hist_kernel(const int* __restrict__ dst, int* __restrict__ cnt) {
    int t = blockIdx.x * blockDim.x + threadIdx.x;
    if (t < NEDGES) atomicAdd(&cnt[dst[t]], 1);
}

// merged part+writeptr: block b computes its global prefix directly from cnt
// (strided sum of cnt[0..b*256), <=160 ints/thread), then intra-chunk scan.
__global__ void scanwrite_kernel(const int* __restrict__ cnt, int* __restrict__ rowptr) {
    __shared__ int sh[256];
    const int b = blockIdx.x, t = threadIdx.x;
    const int lim = b * 256;

    int p = 0;
    for (int i = t; i < lim; i += 256) p += cnt[i];
    sh[t] = p;
    __syncthreads();
    for (int off = 128; off > 0; off >>= 1) {
        if (t < off) sh[t] += sh[t + off];
        __syncthreads();
    }
    const int prefix = sh[0];
    __syncthreads();

    int idx = lim + t;
    int v = cnt[idx];
    sh[t] = v;
    __syncthreads();
    for (int off = 1; off < 256; off <<= 1) {
        int add = (t >= off) ? sh[t - off] : 0;
        __syncthreads();
        sh[t] += add;
        __syncthreads();
    }
    rowptr[idx] = prefix + sh[t] - v;
}

// eidx stored as ushort (NNODES < 65536)
__global__ void fill_kernel(const int* __restrict__ src, const int* __restrict__ dst,
                            const int* __restrict__ rowptr, int* __restrict__ fill,
                            unsigned short* __restrict__ eidx) {
    int e = blockIdx.x * blockDim.x + threadIdx.x;
    if (e < NEDGES) {
        int d = dst[e];
        int pos = rowptr[d] + atomicAdd(&fill[d], 1);
        eidx[pos] = (unsigned short)src[e];
    }
}

// ---------------- all conversions in one kernel (+ zero cnt/fill) ----------------
__global__ void conv_all_kernel(const float* __restrict__ x,
                                const float* __restrict__ W1,
                                const float* __restrict__ W2,
                                const float* __restrict__ W3,
                                unsigned short* __restrict__ xbf,
                                unsigned short* __restrict__ wt1,
                                unsigned short* __restrict__ wt2,
                                unsigned short* __restrict__ wt3,
                                int* __restrict__ czero) {
    const int N0 = NNODES * DIN / 4;
    const int N1 = 2 * DIN * DHID;
    const int N2 = 2 * DHID * DHID;
    const int N3 = 94 * 256;
    int t = blockIdx.x * blockDim.x + threadIdx.x;
    if (t < 2 * NCNT) czero[t] = 0;  // cnt + fill
    if (t < N0) {
        float4 v = ((const float4*)x)[t];
        ushort4 r;
        r.x = f2bf(v.x); r.y = f2bf(v.y); r.z = f2bf(v.z); r.w = f2bf(v.w);
        ((ushort4*)xbf)[t] = r;
    } else if (t < N0 + N1) {
        int u = t - N0;
        int k = u >> 8, n = u & 255;           // W1 [256][256]
        wt1[(size_t)n * 256 + k] = f2bf(W1[u]);
    } else if (t < N0 + N1 + N2) {
        int u = t - N0 - N1;
        int k = u >> 8, n = u & 255;           // W2 [512][256]
        wt2[(size_t)n * 512 + k] = f2bf(W2[u]);
    } else if (t < N0 + N1 + N2 + N3) {
        int u = t - N0 - N1 - N2;
        int n = u >> 8, k = u & 255;           // Wt3 [94][256]
        float v = (n < 47) ? W3[(size_t)k * DOUT + n]
                           : W3[(size_t)(k + DHID) * DOUT + (n - 47)];
        wt3[u] = f2bf(v);
    }
}

// ---------------- mean aggregation (bf16, wave/node, 8x ILP) — FINAL, do not touch ----------------
// Fabric-bound at ~3.1 TB/s L2-miss service (R6/R10 A/B proved instruction
// tweaks and L2-slicing neutral-to-negative).
template <int D>
__global__ void agg_bf16_kernel(const unsigned short* __restrict__ h,
                                const int* __restrict__ rowptr,
                                const unsigned short* __restrict__ eidx,
                                unsigned short* __restrict__ mean) {
    constexpr int VPL = D / 64;  // 2 (D=128) or 4 (D=256)
    const int node = blockIdx.x * (blockDim.x >> 6) + (threadIdx.x >> 6);
    if (node >= NNODES) return;
    const int lane = threadIdx.x & 63;
    const int beg = rowptr[node], end = rowptr[node + 1];
    const unsigned short* hp = h + lane * VPL;

    float acc[VPL];
#pragma unroll
    for (int i = 0; i < VPL; ++i) acc[i] = 0.0f;

    for (int base = beg; base < end; base += 64) {
        int n = min(64, end - base);
        int myidx = (base + lane < end) ? (int)eidx[base + lane] : 0;
        int j = 0;
        for (; j + 8 <= n; j += 8) {
            int s[8];
#pragma unroll
            for (int u = 0; u < 8; ++u) s[u] = __shfl(myidx, j + u);
            if constexpr (VPL == 4) {
                ushort4 v[8];
#pragma unroll
                for (int u = 0; u < 8; ++u) v[u] = *(const ushort4*)(hp + (size_t)s[u] * D);
#pragma unroll
                for (int u = 0; u < 8; ++u) {
                    acc[0] += bf2f(v[u].x); acc[1] += bf2f(v[u].y);
                    acc[2] += bf2f(v[u].z); acc[3] += bf2f(v[u].w);
                }
            } else {
                ushort2 v[8];
#pragma unroll
                for (int u = 0; u < 8; ++u) v[u] = *(const ushort2*)(hp + (size_t)s[u] * D);
#pragma unroll
                for (int u = 0; u < 8; ++u) {
                    acc[0] += bf2f(v[u].x); acc[1] += bf2f(v[u].y);
                }
            }
        }
        for (; j + 4 <= n; j += 4) {
            int s[4];
#pragma unroll
            for (int u = 0; u < 4; ++u) s[u] = __shfl(myidx, j + u);
            if constexpr (VPL == 4) {
                ushort4 v[4];
#pragma unroll
                for (int u = 0; u < 4; ++u) v[u] = *(const ushort4*)(hp + (size_t)s[u] * D);
#pragma unroll
                for (int u = 0; u < 4; ++u) {
                    acc[0] += bf2f(v[u].x); acc[1] += bf2f(v[u].y);
                    acc[2] += bf2f(v[u].z); acc[3] += bf2f(v[u].w);
                }
            } else {
                ushort2 v[4];
#pragma unroll
                for (int u = 0; u < 4; ++u) v[u] = *(const ushort2*)(hp + (size_t)s[u] * D);
#pragma unroll
                for (int u = 0; u < 4; ++u) {
                    acc[0] += bf2f(v[u].x); acc[1] += bf2f(v[u].y);
                }
            }
        }
        for (; j < n; ++j) {
            int s = __shfl(myidx, j);
            if constexpr (VPL == 4) {
                ushort4 v = *(const ushort4*)(hp + (size_t)s * D);
                acc[0] += bf2f(v.x); acc[1] += bf2f(v.y);
                acc[2] += bf2f(v.z); acc[3] += bf2f(v.w);
            } else {
                ushort2 v = *(const ushort2*)(hp + (size_t)s * D);
                acc[0] += bf2f(v.x); acc[1] += bf2f(v.y);
            }
        }
    }
    float inv = (end > beg) ? 1.0f / (float)(end - beg) : 0.0f;
    unsigned short* o = mean + (size_t)node * D + lane * VPL;
    if constexpr (VPL == 4) {
        ushort4 r;
        r.x = f2bf(acc[0] * inv); r.y = f2bf(acc[1] * inv);
        r.z = f2bf(acc[2] * inv); r.w = f2bf(acc[3] * inv);
        *(ushort4*)o = r;
    } else {
        ushort2 r;
        r.x = f2bf(acc[0] * inv); r.y = f2bf(acc[1] * inv);
        *(ushort2*)o = r;
    }
}

// ---------------- layer-3 P aggregation: wide-gather ----------------
__global__ void agg_p_kernel(const unsigned short* __restrict__ P,
                             const int* __restrict__ rowptr,
                             const unsigned short* __restrict__ eidx,
                             float* __restrict__ out) {
    const int node = blockIdx.x * (blockDim.x >> 6) + (threadIdx.x >> 6);
    if (node >= NNODES) return;
    const int lane = threadIdx.x & 63;
    const int g = lane >> 4;
    const int f = lane & 15;
    const bool af = f < 12;
    const int beg = rowptr[node], end = rowptr[node + 1];
    const unsigned short* pp = P + f * 4;

    float a0 = 0.0f, a1 = 0.0f, a2 = 0.0f, a3 = 0.0f;
    for (int base = beg; base < end; base += 64) {
        int n = min(64, end - base);
        int myidx = (base + lane < end) ? (int)eidx[base + lane] : 0;
        int j = 0;
        for (; j + 16 <= n; j += 16) {
            int s0 = __shfl(myidx, j + g);
            int s1 = __shfl(myidx, j + 4 + g);
            int s2 = __shfl(myidx, j + 8 + g);
            int s3 = __shfl(myidx, j + 12 + g);
            if (af) {
                ushort4 v0 = *(const ushort4*)(pp + (size_t)s0 * 48);
                ushort4 v1 = *(const ushort4*)(pp + (size_t)s1 * 48);
                ushort4 v2 = *(const ushort4*)(pp + (size_t)s2 * 48);
                ushort4 v3 = *(const ushort4*)(pp + (size_t)s3 * 48);
                a0 += (bf2f(v0.x) + bf2f(v1.x)) + (bf2f(v2.x) + bf2f(v3.x));
                a1 += (bf2f(v0.y) + bf2f(v1.y)) + (bf2f(v2.y) + bf2f(v3.y));
                a2 += (bf2f(v0.z) + bf2f(v1.z)) + (bf2f(v2.z) + bf2f(v3.z));
                a3 += (bf2f(v0.w) + bf2f(v1.w)) + (bf2f(v2.w) + bf2f(v3.w));
            }
        }
        for (; j + 4 <= n; j += 4) {
            int s0 = __shfl(myidx, j + g);
            if (af) {
                ushort4 v0 = *(const ushort4*)(pp + (size_t)s0 * 48);
                a0 += bf2f(v0.x); a1 += bf2f(v0.y);
                a2 += bf2f(v0.z); a3 += bf2f(v0.w);
            }
        }
        int rem = n - j;
        int srcl = (g < rem) ? (j + g) : 0;   // shfl in uniform flow (R9 lesson)
        int s0 = __shfl(myidx, srcl);
        if (g < rem && af) {
            ushort4 v0 = *(const ushort4*)(pp + (size_t)s0 * 48);
            a0 += bf2f(v0.x); a1 += bf2f(v0.y);
            a2 += bf2f(v0.z); a3 += bf2f(v0.w);
        }
    }
    a0 += __shfl_xor(a0, 16); a1 += __shfl_xor(a1, 16);
    a2 += __shfl_xor(a2, 16); a3 += __shfl_xor(a3, 16);
    a0 += __shfl_xor(a0, 32); a1 += __shfl_xor(a1, 32);
    a2 += __shfl_xor(a2, 32); a3 += __shfl_xor(a3, 32);
    if (lane < 12 && end > beg) {
        float inv = 1.0f / (float)(end - beg);
        float* o = out + (size_t)node * DOUT + lane * 4;
        o[0] += a0 * inv;
        o[1] += a1 * inv;
        o[2] += a2 * inv;
        if (lane * 4 + 3 < DOUT) o[3] += a3 * inv;
    }
}

// ---------------- layers 1-2 GEMM: 64x256 tile, double-buffered gload_lds ----------------
// (256,2): R14 proved (256,3) regresses (VGPR cap 170 -> spills in the K-loop).
template <int D>
__launch_bounds__(256, 2)
__global__ void gemm_fused_kernel(const unsigned short* __restrict__ H,
                                  const unsigned short* __restrict__ Mn,
                                  const unsigned short* __restrict__ Wt,
                                  const float* __restrict__ bias,
                                  unsigned short* __restrict__ hout) {
    constexpr int K = 2 * D;
    constexpr int NK = K / 32;
    __shared__ uint4 As4[2][64 * 4];
    __shared__ uint4 Bs4[2][256 * 4];

    const int tid = threadIdx.x;
    const int lane = tid & 63;
    const int w = tid >> 6;
    const int row0 = blockIdx.x * 64;

    const int lr = lane >> 2;
    const int lslot = lane & 3;
    const int swz = (lslot ^ ((lr >> 1) & 3)) * 8;
    const int arow = w * 16 + lr;
    const size_t abase = (size_t)(row0 + arow) * D;

    f32x4 acc[4][4];
#pragma unroll
    for (int m = 0; m < 4; ++m)
#pragma unroll
        for (int n = 0; n < 4; ++n) {
            f32x4 z = {0.0f, 0.0f, 0.0f, 0.0f};
            acc[m][n] = z;
        }

    const int fr = lane & 15;
    const int sl = lane >> 4;

    {
        GLD16(H + abase + swz, (char*)As4[0] + w * 1024);
#pragma unroll
        for (int c = 0; c < 4; ++c) {
            int brow = (w * 4 + c) * 16 + lr;
            GLD16(Wt + (size_t)brow * K + swz, (char*)Bs4[0] + (w * 4 + c) * 1024);
        }
    }
    __syncthreads();

#pragma unroll
    for (int t = 0; t < NK; ++t) {
        const int cur = t & 1;
        if (t + 1 < NK) {
            const int k0 = (t + 1) * 32;
            const unsigned short* ap = (k0 < D) ? (H + abase + k0 + swz)
                                                : (Mn + abase + (k0 - D) + swz);
            GLD16(ap, (char*)As4[cur ^ 1] + w * 1024);
#pragma unroll
            for (int c = 0; c < 4; ++c) {
                int brow = (w * 4 + c) * 16 + lr;
                GLD16(Wt + (size_t)brow * K + k0 + swz,
                      (char*)Bs4[cur ^ 1] + (w * 4 + c) * 1024);
            }
        }

        short8 af[4], bfv[4];
#pragma unroll
        for (int m = 0; m < 4; ++m) {
            int r = m * 16 + fr;
            union { uint4 u; short8 s; } cc;
            cc.u = As4[cur][r * 4 + (sl ^ ((r >> 1) & 3))];
            af[m] = cc.s;
        }
#pragma unroll
        for (int n = 0; n < 4; ++n) {
            int r = w * 64 + n * 16 + fr;
            union { uint4 u; short8 s; } cc;
            cc.u = Bs4[cur][r * 4 + (sl ^ ((r >> 1) & 3))];
            bfv[n] = cc.s;
        }
#pragma unroll
        for (int m = 0; m < 4; ++m)
#pragma unroll
            for (int n = 0; n < 4; ++n)
                acc[m][n] = __builtin_amdgcn_mfma_f32_16x16x32_bf16(af[m], bfv[n], acc[m][n], 0, 0, 0);

        __syncthreads();
    }

#pragma unroll
    for (int m = 0; m < 4; ++m) {
#pragma unroll
        for (int n = 0; n < 4; ++n) {
            int col = w * 64 + n * 16 + fr;
            float bv = bias[col];
#pragma unroll
            for (int q = 0; q < 4; ++q) {
                int row = row0 + m * 16 + sl * 4 + q;
                float v = fmaxf(acc[m][n][q] + bv, 0.0f);
                hout[(size_t)row * 256 + col] = f2bf(v);
            }
        }
    }
}

// ---------------- layer-3 dual GEMM (known-good, unchanged) ----------------
__launch_bounds__(256, 2)
__global__ void gemm3_kernel(const unsigned short* __restrict__ H,
                             const unsigned short* __restrict__ Wt,
                             const float* __restrict__ bias,
                             float* __restrict__ outp,
                             unsigned short* __restrict__ Pout,
                             int d, int N) {
    const int K = 2 * d;
    __shared__ uint4 AsB[128 * 4];
    __shared__ uint4 BsB[128 * 4];

    const int tid = threadIdx.x;
    const int lane = tid & 63;
    const int wid = tid >> 6;
    const int wr = wid >> 1, wc = wid & 1;
    const int row0 = blockIdx.x * 128;

    const int sr = tid >> 1;
    const int sh = tid & 1;
    const int gar = min(row0 + sr, NNODES - 1);
    const int gbr = min(sr, N - 1);
    const int ssw = (sr >> 1) & 3;

    f32x4 acc[4][4];
#pragma unroll
    for (int m = 0; m < 4; ++m)
#pragma unroll
        for (int n = 0; n < 4; ++n) {
            f32x4 z = {0.0f, 0.0f, 0.0f, 0.0f};
            acc[m][n] = z;
        }

    for (int k0 = 0; k0 < K; k0 += 32) {
        {
            const unsigned short* p = H + (size_t)gar * K + k0 + sh * 16;
            uint4 v0 = *(const uint4*)p;
            uint4 v1 = *(const uint4*)(p + 8);
            AsB[sr * 4 + ((2 * sh) ^ ssw)]     = v0;
            AsB[sr * 4 + ((2 * sh + 1) ^ ssw)] = v1;
        }
        {
            const unsigned short* p = Wt + (size_t)gbr * K + k0 + sh * 16;
            uint4 v0 = *(const uint4*)p;
            uint4 v1 = *(const uint4*)(p + 8);
            BsB[sr * 4 + ((2 * sh) ^ ssw)]     = v0;
            BsB[sr * 4 + ((2 * sh + 1) ^ ssw)] = v1;
        }
        __syncthreads();

        short8 af[4], bfv[4];
        const int fr = lane & 15;
        const int slot = lane >> 4;
#pragma unroll
        for (int m = 0; m < 4; ++m) {
            int r = wr * 64 + m * 16 + fr;
            union { uint4 u; short8 s; } cc;
            cc.u = AsB[r * 4 + (slot ^ ((r >> 1) & 3))];
            af[m] = cc.s;
        }
#pragma unroll
        for (int n = 0; n < 4; ++n) {
            int r = wc * 64 + n * 16 + fr;
            union { uint4 u; short8 s; } cc;
            cc.u = BsB[r * 4 + (slot ^ ((r >> 1) & 3))];
            bfv[n] = cc.s;
        }
#pragma unroll
        for (int m = 0; m < 4; ++m)
#pragma unroll
            for (int n = 0; n < 4; ++n)
                acc[m][n] = __builtin_amdgcn_mfma_f32_16x16x32_bf16(af[m], bfv[n], acc[m][n], 0, 0, 0);
        __syncthreads();
    }

#pragma unroll
    for (int m = 0; m < 4; ++m) {
#pragma unroll
        for (int n = 0; n < 4; ++n) {
            int col = wc * 64 + n * 16 + (lane & 15);
            if (col >= N) continue;
            float bv = (col < 47) ? bias[col] : 0.0f;
#pragma unroll
            for (int q = 0; q < 4; ++q) {
                int row = row0 + wr * 64 + m * 16 + (lane >> 4) * 4 + q;
                if (row < NNODES) {
                    float v = acc[m][n][q] + bv;
                    if (col < 47) outp[(size_t)row * DOUT + col] = v;
                    else Pout[(size_t)row * 48 + (col - 47)] = f2bf(v);
                }
            }
        }
    }
}

extern "C" void kernel_launch(void* const* d_in, const int* in_sizes, int n_in,
                              void* d_out, int out_size, void* d_ws, size_t ws_size,
                              hipStream_t stream) {
    const float* x  = (const float*)d_in[0];
    const float* W1 = (const float*)d_in[1];
    const float* b1 = (const float*)d_in[2];
    const float* W2 = (const float*)d_in[3];
    const float* b2 = (const float*)d_in[4];
    const float* W3 = (const float*)d_in[5];
    const float* b3 = (const float*)d_in[6];
    const int* src  = (const int*)d_in[7];
    const int* dst  = (const int*)d_in[8];
    float* out = (float*)d_out;

    int* rowptr  = (int*)d_ws;                          // NCNT ints
    unsigned short* eidx = (unsigned short*)(rowptr + NCNT);  // NEDGES ushort
    int* cnt     = (int*)(eidx + NEDGES);               // NCNT
    int* fill    = cnt + NCNT;                          // NCNT (contiguous after cnt)
    unsigned short* xbf  = (unsigned short*)(fill + NCNT);
    unsigned short* h1   = xbf + (size_t)NNODES * DIN;
    unsigned short* h2   = h1 + (size_t)NNODES * DHID;
    unsigned short* mean = h2 + (size_t)NNODES * DHID;
    unsigned short* wt1  = mean + (size_t)NNODES * DHID;
    unsigned short* wt2  = wt1 + 2 * DIN * DHID;
    unsigned short* wt3  = wt2 + 2 * DHID * DHID;
    unsigned short* P    = mean;  // layer-3 reuse (mean dead by then)

    // ---- conversions + zero cnt/fill ----
    {
        const int NT = NNODES * DIN / 4 + 2 * DIN * DHID + 2 * DHID * DHID + 94 * 256;
        conv_all_kernel<<<(NT + 255) / 256, 256, 0, stream>>>(x, W1, W2, W3, xbf, wt1, wt2, wt3, cnt);
    }

    // ---- CSR build (3 kernels) ----
    hist_kernel<<<(NEDGES + 255) / 256, 256, 0, stream>>>(dst, cnt);
    scanwrite_kernel<<<NPART, 256, 0, stream>>>(cnt, rowptr);
    fill_kernel<<<(NEDGES + 255) / 256, 256, 0, stream>>>(src, dst, rowptr, fill, eidx);

    // ---- layer 1: d=128 -> 256
    agg_bf16_kernel<DIN><<<NNODES / 4, 256, 0, stream>>>(xbf, rowptr, eidx, mean);
    gemm_fused_kernel<DIN><<<NNODES / 64, 256, 0, stream>>>(xbf, mean, wt1, b1, h1);

    // ---- layer 2: d=256 -> 256
    agg_bf16_kernel<DHID><<<NNODES / 4, 256, 0, stream>>>(h1, rowptr, eidx, mean);
    gemm_fused_kernel<DHID><<<NNODES / 64, 256, 0, stream>>>(h1, mean, wt2, b2, h2);

    // ---- layer 3: dual GEMM then P-aggregate
    gemm3_kernel<<<(NNODES + 127) / 128, 256, 0, stream>>>(h2, wt3, b3, out, P, DHID / 2, 94);
    agg_p_kernel<<<NNODES / 4, 256, 0, stream>>>(P, rowptr, eidx, out);
}

// Round 16
// 213.055 us; speedup vs baseline: 1.0823x; 1.0823x over previous
//
#include <hip/hip_runtime.h>

#define NNODES 40000
#define NEDGES 640000
#define DIN 128
#define DHID 256
#define DOUT 47
#define NCNT 40960
#define NPART (NCNT / 256)

typedef __attribute__((ext_vector_type(8))) short short8;
typedef __attribute__((ext_vector_type(4))) float f32x4;

#define GLD16(gp, lp)                                                        \
    __builtin_amdgcn_global_load_lds(                                        \
        (const __attribute__((address_space(1))) void*)(gp),                 \
        (__attribute__((address_space(3))) void*)(lp), 16, 0, 0)

__device__ inline float bf2f(unsigned short u) {
    union { unsigned int i; float f; } c; c.i = ((unsigned int)u) << 16; return c.f;
}
__device__ inline unsigned short f2bf(float f) {
    union { float f; unsigned int i; } c; c.f = f;
    unsigned int x = c.i;
    x += 0x7fff + ((x >> 16) & 1);  // RNE
    return (unsigned short)(x >> 16);
}

// ---------------- CSR build (4-kernel chain) ----------------
// R12: coop grid.sync is ~20x worse than kernel boundaries.
// R15: merging part+writeptr into one kernel creates a ~160-deep serial
// load chain per thread (non-unrolled runtime loop) costing ~17 us. Keep
// the two tiny parallel passes + boundary instead.
__global__ void hist_kernel(const int* __restrict__ dst, int* __restrict__ cnt) {
    int t = blockIdx.x * blockDim.x + threadIdx.x;
    if (t < NEDGES) atomicAdd(&cnt[dst[t]], 1);
}

__global__ void part_kernel(const int* __restrict__ cnt, int* __restrict__ part) {
    int b = blockIdx.x, t = threadIdx.x;
    int v = cnt[b * 256 + t];
#pragma unroll
    for (int off = 32; off > 0; off >>= 1) v += __shfl_down(v, off);
    __shared__ int ws[4];
    if ((t & 63) == 0) ws[t >> 6] = v;
    __syncthreads();
    if (t == 0) part[b] = ws[0] + ws[1] + ws[2] + ws[3];
}

// scan of part[] (160 entries) + intra-block scan + write
__global__ void writeptr_kernel(const int* __restrict__ cnt, const int* __restrict__ part,
                                int* __restrict__ rowptr) {
    __shared__ int shp[256];
    __shared__ int sh[256];
    int b = blockIdx.x, t = threadIdx.x;
    int pv = (t < NPART) ? part[t] : 0;
    shp[t] = pv;
    __syncthreads();
    for (int off = 1; off < 256; off <<= 1) {
        int add = (t >= off) ? shp[t - off] : 0;
        __syncthreads();
        shp[t] += add;
        __syncthreads();
    }
    int partoff = (b == 0) ? 0 : shp[b - 1];
    int idx = b * 256 + t;
    int v = cnt[idx];
    sh[t] = v;
    __syncthreads();
    for (int off = 1; off < 256; off <<= 1) {
        int add = (t >= off) ? sh[t - off] : 0;
        __syncthreads();
        sh[t] += add;
        __syncthreads();
    }
    rowptr[idx] = partoff + sh[t] - v;
}

// eidx stored as ushort (NNODES < 65536)
__global__ void fill_kernel(const int* __restrict__ src, const int* __restrict__ dst,
                            const int* __restrict__ rowptr, int* __restrict__ fill,
                            unsigned short* __restrict__ eidx) {
    int e = blockIdx.x * blockDim.x + threadIdx.x;
    if (e < NEDGES) {
        int d = dst[e];
        int pos = rowptr[d] + atomicAdd(&fill[d], 1);
        eidx[pos] = (unsigned short)src[e];
    }
}

// ---------------- all conversions in one kernel (+ zero cnt/fill) ----------------
__global__ void conv_all_kernel(const float* __restrict__ x,
                                const float* __restrict__ W1,
                                const float* __restrict__ W2,
                                const float* __restrict__ W3,
                                unsigned short* __restrict__ xbf,
                                unsigned short* __restrict__ wt1,
                                unsigned short* __restrict__ wt2,
                                unsigned short* __restrict__ wt3,
                                int* __restrict__ czero) {
    const int N0 = NNODES * DIN / 4;
    const int N1 = 2 * DIN * DHID;
    const int N2 = 2 * DHID * DHID;
    const int N3 = 94 * 256;
    int t = blockIdx.x * blockDim.x + threadIdx.x;
    if (t < 2 * NCNT) czero[t] = 0;  // cnt + fill
    if (t < N0) {
        float4 v = ((const float4*)x)[t];
        ushort4 r;
        r.x = f2bf(v.x); r.y = f2bf(v.y); r.z = f2bf(v.z); r.w = f2bf(v.w);
        ((ushort4*)xbf)[t] = r;
    } else if (t < N0 + N1) {
        int u = t - N0;
        int k = u >> 8, n = u & 255;           // W1 [256][256]
        wt1[(size_t)n * 256 + k] = f2bf(W1[u]);
    } else if (t < N0 + N1 + N2) {
        int u = t - N0 - N1;
        int k = u >> 8, n = u & 255;           // W2 [512][256]
        wt2[(size_t)n * 512 + k] = f2bf(W2[u]);
    } else if (t < N0 + N1 + N2 + N3) {
        int u = t - N0 - N1 - N2;
        int n = u >> 8, k = u & 255;           // Wt3 [94][256]
        float v = (n < 47) ? W3[(size_t)k * DOUT + n]
                           : W3[(size_t)(k + DHID) * DOUT + (n - 47)];
        wt3[u] = f2bf(v);
    }
}

// ---------------- mean aggregation (bf16, wave/node, 8x ILP) — FINAL, do not touch ----------------
// Fabric-bound at ~3.1 TB/s L2-miss service (R6/R10 A/B proved instruction
// tweaks and L2-slicing neutral-to-negative).
template <int D>
__global__ void agg_bf16_kernel(const unsigned short* __restrict__ h,
                                const int* __restrict__ rowptr,
                                const unsigned short* __restrict__ eidx,
                                unsigned short* __restrict__ mean) {
    constexpr int VPL = D / 64;  // 2 (D=128) or 4 (D=256)
    const int node = blockIdx.x * (blockDim.x >> 6) + (threadIdx.x >> 6);
    if (node >= NNODES) return;
    const int lane = threadIdx.x & 63;
    const int beg = rowptr[node], end = rowptr[node + 1];
    const unsigned short* hp = h + lane * VPL;

    float acc[VPL];
#pragma unroll
    for (int i = 0; i < VPL; ++i) acc[i] = 0.0f;

    for (int base = beg; base < end; base += 64) {
        int n = min(64, end - base);
        int myidx = (base + lane < end) ? (int)eidx[base + lane] : 0;
        int j = 0;
        for (; j + 8 <= n; j += 8) {
            int s[8];
#pragma unroll
            for (int u = 0; u < 8; ++u) s[u] = __shfl(myidx, j + u);
            if constexpr (VPL == 4) {
                ushort4 v[8];
#pragma unroll
                for (int u = 0; u < 8; ++u) v[u] = *(const ushort4*)(hp + (size_t)s[u] * D);
#pragma unroll
                for (int u = 0; u < 8; ++u) {
                    acc[0] += bf2f(v[u].x); acc[1] += bf2f(v[u].y);
                    acc[2] += bf2f(v[u].z); acc[3] += bf2f(v[u].w);
                }
            } else {
                ushort2 v[8];
#pragma unroll
                for (int u = 0; u < 8; ++u) v[u] = *(const ushort2*)(hp + (size_t)s[u] * D);
#pragma unroll
                for (int u = 0; u < 8; ++u) {
                    acc[0] += bf2f(v[u].x); acc[1] += bf2f(v[u].y);
                }
            }
        }
        for (; j + 4 <= n; j += 4) {
            int s[4];
#pragma unroll
            for (int u = 0; u < 4; ++u) s[u] = __shfl(myidx, j + u);
            if constexpr (VPL == 4) {
                ushort4 v[4];
#pragma unroll
                for (int u = 0; u < 4; ++u) v[u] = *(const ushort4*)(hp + (size_t)s[u] * D);
#pragma unroll
                for (int u = 0; u < 4; ++u) {
                    acc[0] += bf2f(v[u].x); acc[1] += bf2f(v[u].y);
                    acc[2] += bf2f(v[u].z); acc[3] += bf2f(v[u].w);
                }
            } else {
                ushort2 v[4];
#pragma unroll
                for (int u = 0; u < 4; ++u) v[u] = *(const ushort2*)(hp + (size_t)s[u] * D);
#pragma unroll
                for (int u = 0; u < 4; ++u) {
                    acc[0] += bf2f(v[u].x); acc[1] += bf2f(v[u].y);
                }
            }
        }
        for (; j < n; ++j) {
            int s = __shfl(myidx, j);
            if constexpr (VPL == 4) {
                ushort4 v = *(const ushort4*)(hp + (size_t)s * D);
                acc[0] += bf2f(v.x); acc[1] += bf2f(v.y);
                acc[2] += bf2f(v.z); acc[3] += bf2f(v.w);
            } else {
                ushort2 v = *(const ushort2*)(hp + (size_t)s * D);
                acc[0] += bf2f(v.x); acc[1] += bf2f(v.y);
            }
        }
    }
    float inv = (end > beg) ? 1.0f / (float)(end - beg) : 0.0f;
    unsigned short* o = mean + (size_t)node * D + lane * VPL;
    if constexpr (VPL == 4) {
        ushort4 r;
        r.x = f2bf(acc[0] * inv); r.y = f2bf(acc[1] * inv);
        r.z = f2bf(acc[2] * inv); r.w = f2bf(acc[3] * inv);
        *(ushort4*)o = r;
    } else {
        ushort2 r;
        r.x = f2bf(acc[0] * inv); r.y = f2bf(acc[1] * inv);
        *(ushort2*)o = r;
    }
}

// ---------------- layer-3 P aggregation: wide-gather ----------------
__global__ void agg_p_kernel(const unsigned short* __restrict__ P,
                             const int* __restrict__ rowptr,
                             const unsigned short* __restrict__ eidx,
                             float* __restrict__ out) {
    const int node = blockIdx.x * (blockDim.x >> 6) + (threadIdx.x >> 6);
    if (node >= NNODES) return;
    const int lane = threadIdx.x & 63;
    const int g = lane >> 4;
    const int f = lane & 15;
    const bool af = f < 12;
    const int beg = rowptr[node], end = rowptr[node + 1];
    const unsigned short* pp = P + f * 4;

    float a0 = 0.0f, a1 = 0.0f, a2 = 0.0f, a3 = 0.0f;
    for (int base = beg; base < end; base += 64) {
        int n = min(64, end - base);
        int myidx = (base + lane < end) ? (int)eidx[base + lane] : 0;
        int j = 0;
        for (; j + 16 <= n; j += 16) {
            int s0 = __shfl(myidx, j + g);
            int s1 = __shfl(myidx, j + 4 + g);
            int s2 = __shfl(myidx, j + 8 + g);
            int s3 = __shfl(myidx, j + 12 + g);
            if (af) {
                ushort4 v0 = *(const ushort4*)(pp + (size_t)s0 * 48);
                ushort4 v1 = *(const ushort4*)(pp + (size_t)s1 * 48);
                ushort4 v2 = *(const ushort4*)(pp + (size_t)s2 * 48);
                ushort4 v3 = *(const ushort4*)(pp + (size_t)s3 * 48);
                a0 += (bf2f(v0.x) + bf2f(v1.x)) + (bf2f(v2.x) + bf2f(v3.x));
                a1 += (bf2f(v0.y) + bf2f(v1.y)) + (bf2f(v2.y) + bf2f(v3.y));
                a2 += (bf2f(v0.z) + bf2f(v1.z)) + (bf2f(v2.z) + bf2f(v3.z));
                a3 += (bf2f(v0.w) + bf2f(v1.w)) + (bf2f(v2.w) + bf2f(v3.w));
            }
        }
        for (; j + 4 <= n; j += 4) {
            int s0 = __shfl(myidx, j + g);
            if (af) {
                ushort4 v0 = *(const ushort4*)(pp + (size_t)s0 * 48);
                a0 += bf2f(v0.x); a1 += bf2f(v0.y);
                a2 += bf2f(v0.z); a3 += bf2f(v0.w);
            }
        }
        int rem = n - j;
        int srcl = (g < rem) ? (j + g) : 0;   // shfl in uniform flow (R9 lesson)
        int s0 = __shfl(myidx, srcl);
        if (g < rem && af) {
            ushort4 v0 = *(const ushort4*)(pp + (size_t)s0 * 48);
            a0 += bf2f(v0.x); a1 += bf2f(v0.y);
            a2 += bf2f(v0.z); a3 += bf2f(v0.w);
        }
    }
    a0 += __shfl_xor(a0, 16); a1 += __shfl_xor(a1, 16);
    a2 += __shfl_xor(a2, 16); a3 += __shfl_xor(a3, 16);
    a0 += __shfl_xor(a0, 32); a1 += __shfl_xor(a1, 32);
    a2 += __shfl_xor(a2, 32); a3 += __shfl_xor(a3, 32);
    if (lane < 12 && end > beg) {
        float inv = 1.0f / (float)(end - beg);
        float* o = out + (size_t)node * DOUT + lane * 4;
        o[0] += a0 * inv;
        o[1] += a1 * inv;
        o[2] += a2 * inv;
        if (lane * 4 + 3 < DOUT) o[3] += a3 * inv;
    }
}

// ---------------- layers 1-2 GEMM: 64x256 tile, double-buffered gload_lds ----------------
template <int D>
__launch_bounds__(256, 2)
__global__ void gemm_fused_kernel(const unsigned short* __restrict__ H,
                                  const unsigned short* __restrict__ Mn,
                                  const unsigned short* __restrict__ Wt,
                                  const float* __restrict__ bias,
                                  unsigned short* __restrict__ hout) {
    constexpr int K = 2 * D;
    constexpr int NK = K / 32;
    __shared__ uint4 As4[2][64 * 4];
    __shared__ uint4 Bs4[2][256 * 4];

    const int tid = threadIdx.x;
    const int lane = tid & 63;
    const int w = tid >> 6;
    const int row0 = blockIdx.x * 64;

    const int lr = lane >> 2;
    const int lslot = lane & 3;
    const int swz = (lslot ^ ((lr >> 1) & 3)) * 8;
    const int arow = w * 16 + lr;
    const size_t abase = (size_t)(row0 + arow) * D;

    f32x4 acc[4][4];
#pragma unroll
    for (int m = 0; m < 4; ++m)
#pragma unroll
        for (int n = 0; n < 4; ++n) {
            f32x4 z = {0.0f, 0.0f, 0.0f, 0.0f};
            acc[m][n] = z;
        }

    const int fr = lane & 15;
    const int sl = lane >> 4;

    {
        GLD16(H + abase + swz, (char*)As4[0] + w * 1024);
#pragma unroll
        for (int c = 0; c < 4; ++c) {
            int brow = (w * 4 + c) * 16 + lr;
            GLD16(Wt + (size_t)brow * K + swz, (char*)Bs4[0] + (w * 4 + c) * 1024);
        }
    }
    __syncthreads();

#pragma unroll
    for (int t = 0; t < NK; ++t) {
        const int cur = t & 1;
        if (t + 1 < NK) {
            const int k0 = (t + 1) * 32;
            const unsigned short* ap = (k0 < D) ? (H + abase + k0 + swz)
                                                : (Mn + abase + (k0 - D) + swz);
            GLD16(ap, (char*)As4[cur ^ 1] + w * 1024);
#pragma unroll
            for (int c = 0; c < 4; ++c) {
                int brow = (w * 4 + c) * 16 + lr;
                GLD16(Wt + (size_t)brow * K + k0 + swz,
                      (char*)Bs4[cur ^ 1] + (w * 4 + c) * 1024);
            }
        }

        short8 af[4], bfv[4];
#pragma unroll
        for (int m = 0; m < 4; ++m) {
            int r = m * 16 + fr;
            union { uint4 u; short8 s; } cc;
            cc.u = As4[cur][r * 4 + (sl ^ ((r >> 1) & 3))];
            af[m] = cc.s;
        }
#pragma unroll
        for (int n = 0; n < 4; ++n) {
            int r = w * 64 + n * 16 + fr;
            union { uint4 u; short8 s; } cc;
            cc.u = Bs4[cur][r * 4 + (sl ^ ((r >> 1) & 3))];
            bfv[n] = cc.s;
        }
#pragma unroll
        for (int m = 0; m < 4; ++m)
#pragma unroll
            for (int n = 0; n < 4; ++n)
                acc[m][n] = __builtin_amdgcn_mfma_f32_16x16x32_bf16(af[m], bfv[n], acc[m][n], 0, 0, 0);

        __syncthreads();
    }

#pragma unroll
    for (int m = 0; m < 4; ++m) {
#pragma unroll
        for (int n = 0; n < 4; ++n) {
            int col = w * 64 + n * 16 + fr;
            float bv = bias[col];
#pragma unroll
            for (int q = 0; q < 4; ++q) {
                int row = row0 + m * 16 + sl * 4 + q;
                float v = fmaxf(acc[m][n][q] + bv, 0.0f);
                hout[(size_t)row * 256 + col] = f2bf(v);
            }
        }
    }
}

// ---------------- layer-3 dual GEMM (known-good, unchanged) ----------------
__launch_bounds__(256, 2)
__global__ void gemm3_kernel(const unsigned short* __restrict__ H,
                             const unsigned short* __restrict__ Wt,
                             const float* __restrict__ bias,
                             float* __restrict__ outp,
                             unsigned short* __restrict__ Pout,
                             int d, int N) {
    const int K = 2 * d;
    __shared__ uint4 AsB[128 * 4];
    __shared__ uint4 BsB[128 * 4];

    const int tid = threadIdx.x;
    const int lane = tid & 63;
    const int wid = tid >> 6;
    const int wr = wid >> 1, wc = wid & 1;
    const int row0 = blockIdx.x * 128;

    const int sr = tid >> 1;
    const int sh = tid & 1;
    const int gar = min(row0 + sr, NNODES - 1);
    const int gbr = min(sr, N - 1);
    const int ssw = (sr >> 1) & 3;

    f32x4 acc[4][4];
#pragma unroll
    for (int m = 0; m < 4; ++m)
#pragma unroll
        for (int n = 0; n < 4; ++n) {
            f32x4 z = {0.0f, 0.0f, 0.0f, 0.0f};
            acc[m][n] = z;
        }

    for (int k0 = 0; k0 < K; k0 += 32) {
        {
            const unsigned short* p = H + (size_t)gar * K + k0 + sh * 16;
            uint4 v0 = *(const uint4*)p;
            uint4 v1 = *(const uint4*)(p + 8);
            AsB[sr * 4 + ((2 * sh) ^ ssw)]     = v0;
            AsB[sr * 4 + ((2 * sh + 1) ^ ssw)] = v1;
        }
        {
            const unsigned short* p = Wt + (size_t)gbr * K + k0 + sh * 16;
            uint4 v0 = *(const uint4*)p;
            uint4 v1 = *(const uint4*)(p + 8);
            BsB[sr * 4 + ((2 * sh) ^ ssw)]     = v0;
            BsB[sr * 4 + ((2 * sh + 1) ^ ssw)] = v1;
        }
        __syncthreads();

        short8 af[4], bfv[4];
        const int fr = lane & 15;
        const int slot = lane >> 4;
#pragma unroll
        for (int m = 0; m < 4; ++m) {
            int r = wr * 64 + m * 16 + fr;
            union { uint4 u; short8 s; } cc;
            cc.u = AsB[r * 4 + (slot ^ ((r >> 1) & 3))];
            af[m] = cc.s;
        }
#pragma unroll
        for (int n = 0; n < 4; ++n) {
            int r = wc * 64 + n * 16 + fr;
            union { uint4 u; short8 s; } cc;
            cc.u = BsB[r * 4 + (slot ^ ((r >> 1) & 3))];
            bfv[n] = cc.s;
        }
#pragma unroll
        for (int m = 0; m < 4; ++m)
#pragma unroll
            for (int n = 0; n < 4; ++n)
                acc[m][n] = __builtin_amdgcn_mfma_f32_16x16x32_bf16(af[m], bfv[n], acc[m][n], 0, 0, 0);
        __syncthreads();
    }

#pragma unroll
    for (int m = 0; m < 4; ++m) {
#pragma unroll
        for (int n = 0; n < 4; ++n) {
            int col = wc * 64 + n * 16 + (lane & 15);
            if (col >= N) continue;
            float bv = (col < 47) ? bias[col] : 0.0f;
#pragma unroll
            for (int q = 0; q < 4; ++q) {
                int row = row0 + wr * 64 + m * 16 + (lane >> 4) * 4 + q;
                if (row < NNODES) {
                    float v = acc[m][n][q] + bv;
                    if (col < 47) outp[(size_t)row * DOUT + col] = v;
                    else Pout[(size_t)row * 48 + (col - 47)] = f2bf(v);
                }
            }
        }
    }
}

extern "C" void kernel_launch(void* const* d_in, const int* in_sizes, int n_in,
                              void* d_out, int out_size, void* d_ws, size_t ws_size,
                              hipStream_t stream) {
    const float* x  = (const float*)d_in[0];
    const float* W1 = (const float*)d_in[1];
    const float* b1 = (const float*)d_in[2];
    const float* W2 = (const float*)d_in[3];
    const float* b2 = (const float*)d_in[4];
    const float* W3 = (const float*)d_in[5];
    const float* b3 = (const float*)d_in[6];
    const int* src  = (const int*)d_in[7];
    const int* dst  = (const int*)d_in[8];
    float* out = (float*)d_out;

    int* rowptr  = (int*)d_ws;                          // NCNT ints
    unsigned short* eidx = (unsigned short*)(rowptr + NCNT);  // NEDGES ushort
    int* cnt     = (int*)(eidx + NEDGES);               // NCNT
    int* fill    = cnt + NCNT;                          // NCNT (contiguous after cnt)
    int* part    = fill + NCNT;                         // 256
    unsigned short* xbf  = (unsigned short*)(part + 256);
    unsigned short* h1   = xbf + (size_t)NNODES * DIN;
    unsigned short* h2   = h1 + (size_t)NNODES * DHID;
    unsigned short* mean = h2 + (size_t)NNODES * DHID;
    unsigned short* wt1  = mean + (size_t)NNODES * DHID;
    unsigned short* wt2  = wt1 + 2 * DIN * DHID;
    unsigned short* wt3  = wt2 + 2 * DHID * DHID;
    unsigned short* P    = mean;  // layer-3 reuse (mean dead by then)

    // ---- conversions + zero cnt/fill (single kernel, runs first) ----
    {
        const int NT = NNODES * DIN / 4 + 2 * DIN * DHID + 2 * DHID * DHID + 94 * 256;
        conv_all_kernel<<<(NT + 255) / 256, 256, 0, stream>>>(x, W1, W2, W3, xbf, wt1, wt2, wt3, cnt);
    }

    // ---- CSR build ----
    hist_kernel<<<(NEDGES + 255) / 256, 256, 0, stream>>>(dst, cnt);
    part_kernel<<<NPART, 256, 0, stream>>>(cnt, part);
    writeptr_kernel<<<NPART, 256, 0, stream>>>(cnt, part, rowptr);
    fill_kernel<<<(NEDGES + 255) / 256, 256, 0, stream>>>(src, dst, rowptr, fill, eidx);

    // ---- layer 1: d=128 -> 256
    agg_bf16_kernel<DIN><<<NNODES / 4, 256, 0, stream>>>(xbf, rowptr, eidx, mean);
    gemm_fused_kernel<DIN><<<NNODES / 64, 256, 0, stream>>>(xbf, mean, wt1, b1, h1);

    // ---- layer 2: d=256 -> 256
    agg_bf16_kernel<DHID><<<NNODES / 4, 256, 0, stream>>>(h1, rowptr, eidx, mean);
    gemm_fused_kernel<DHID><<<NNODES / 64, 256, 0, stream>>>(h1, mean, wt2, b2, h2);

    // ---- layer 3: dual GEMM then P-aggregate
    gemm3_kernel<<<(NNODES + 127) / 128, 256, 0, stream>>>(h2, wt3, b3, out, P, DHID / 2, 94);
    agg_p_kernel<<<NNODES / 4, 256, 0, stream>>>(P, rowptr, eidx, out);
}